// Round 4
// baseline (340.910 us; speedup 1.0000x reference)
//
#include <hip/hip_runtime.h>
#include <hip/hip_bf16.h>
#include <stdint.h>

#define BATCH  8192
#define DIN    2048
#define DOUT   2048
#define NB     256
#define KSEL   26   // ceil(0.1*256)

typedef __attribute__((ext_vector_type(2))) float f32x2;
typedef __attribute__((ext_vector_type(4))) float f32x4;
typedef __attribute__((ext_vector_type(8))) __bf16 bf16x8;
typedef __attribute__((ext_vector_type(8))) unsigned short u16x8;
typedef __attribute__((ext_vector_type(4))) unsigned short u16x4;

__device__ __forceinline__ float bf2f(unsigned short u){
  union { unsigned int i; float f; } v; v.i = ((unsigned int)u) << 16; return v.f;
}
__device__ __forceinline__ unsigned short f2bf(float f){
  union { float f; unsigned int i; } v; v.f = f;
  unsigned int x = v.i;
  return (unsigned short)((x + 0x7FFFu + ((x >> 16) & 1u)) >> 16);  // RNE
}
// native cast path — compiler emits v_cvt_pk_bf16_f32 for pairs (RNE)
__device__ __forceinline__ unsigned short f2bf_c(float f){
  __bf16 b = (__bf16)f;
  union { __bf16 b; unsigned short u; } v; v.b = b; return v.u;
}

// ---------------- K0b: W -> W^T bf16 (wt[n][k] = W[k][n]) ----------------
__global__ __launch_bounds__(256) void conv_wt(const float* __restrict__ w, unsigned short* __restrict__ wt)
{
  __shared__ float tl[64][65];
  const int k0 = blockIdx.x * 64;
  const int n0 = blockIdx.y * 64;
  const int c  = threadIdx.x & 63;
  const int r4 = threadIdx.x >> 6;
  #pragma unroll
  for (int i = 0; i < 16; i++){
    const int r = r4 * 16 + i;
    tl[r][c] = w[(size_t)(k0 + r) * DOUT + n0 + c];
  }
  __syncthreads();
  #pragma unroll
  for (int i = 0; i < 16; i++){
    const int n = r4 * 16 + i;
    wt[(size_t)(n0 + n) * DIN + k0 + c] = f2bf(tl[c][n]);
  }
}

// ---------------- K1: gate GEMM, f32 (accuracy-critical for top-k) ----------
// LDS-free: x loads are wave-uniform (1 line/instr, lane-broadcast), gw loads
// are 1KB-contiguous per instr from L2 (gw is 2MB, L2-resident, 256x reuse).
// Thread tile 8 rows x 4 cols; wave = one row-group (t = rt*64 + ct).
// Block = 4 waves = 32 rows x 256 cols; K-split 2 -> 512 blocks (2/SIMD).
// FMA chain per output: fmaf, k ascending, per-1024 split -> gate values
// bit-identical to the previously passing versions. Also emits bf16 x
// (each element exactly once grid-wide: lane ct==r stores row r's chunk).
__global__ __launch_bounds__(256) void gate_gemm(
    const float* __restrict__ x, const float* __restrict__ gw,
    float* __restrict__ part, unsigned short* __restrict__ xb)
{
  const int b0   = blockIdx.x * 32;
  const int ks   = blockIdx.y;        // K-split 0/1
  const int t    = threadIdx.x;
  const int ct   = t & 63;            // lane: 4 cols at ct*4
  const int rt   = t >> 6;            // wave: rows rt*8..rt*8+7
  const int row0 = b0 + rt * 8;
  const int koff = ks * 1024;

  f32x4 acc[8];
  #pragma unroll
  for (int r = 0; r < 8; r++) acc[r] = (f32x4)0.0f;

  const float* xp = x  + (size_t)row0 * DIN + koff;
  const float* wp = gw + (size_t)koff * NB + ct * 4;

  for (int kc = 0; kc < 1024; kc += 8){
    f32x4 xv[8][2];                   // all indices compile-time (stays in regs)
    #pragma unroll
    for (int r = 0; r < 8; r++){
      xv[r][0] = *(const f32x4*)(xp + (size_t)r * DIN + kc);
      xv[r][1] = *(const f32x4*)(xp + (size_t)r * DIN + kc + 4);
    }
    #pragma unroll
    for (int j = 0; j < 8; j++){
      f32x4 wv = *(const f32x4*)(wp + (size_t)(kc + j) * NB);
      #pragma unroll
      for (int r = 0; r < 8; r++){
        const float xr = xv[r][j >> 2][j & 3];
        acc[r][0] = fmaf(xr, wv[0], acc[r][0]);
        acc[r][1] = fmaf(xr, wv[1], acc[r][1]);
        acc[r][2] = fmaf(xr, wv[2], acc[r][2]);
        acc[r][3] = fmaf(xr, wv[3], acc[r][3]);
      }
    }
    // bf16-x emission: lane ct==r stores row r's 8 values (16B, aligned)
    #pragma unroll
    for (int r = 0; r < 8; r++){
      if (ct == r){
        u16x8 o;
        #pragma unroll
        for (int j = 0; j < 8; j++) o[j] = f2bf_c(xv[r][j >> 2][j & 3]);
        *(u16x8*)&xb[(size_t)(row0 + r) * DIN + koff + kc] = o;
      }
    }
  }

  float* dst = part + (size_t)ks * BATCH * NB;
  #pragma unroll
  for (int r = 0; r < 8; r++)
    *(f32x4*)&dst[(size_t)(row0 + r) * NB + ct * 4] = acc[r];
}

// ---------------- K2: reduce partials + bias, top-26 threshold, renormalize --
__global__ __launch_bounds__(256) void topk(float* __restrict__ part, const float* __restrict__ gb)
{
  const int lane = threadIdx.x & 63;
  const int row  = blockIdx.x * 4 + (threadIdx.x >> 6);
  f32x4* p0 = (f32x4*)&part[(size_t)row * NB];
  const f32x4* p1 = (const f32x4*)&part[(size_t)(BATCH + row) * NB];
  const f32x4* gbv = (const f32x4*)gb;
  f32x4 v = p0[lane] + p1[lane] + gbv[lane];

  const float NEG = -3.402823466e38f;
  float w0 = v[0], w1 = v[1], w2 = v[2], w3 = v[3];
  float thr = 0.f;
  for (int it = 0; it < KSEL; it++){
    float lm = fmaxf(fmaxf(w0, w1), fmaxf(w2, w3));
    float wm = lm;
    #pragma unroll
    for (int off = 32; off; off >>= 1) wm = fmaxf(wm, __shfl_xor(wm, off, 64));
    unsigned long long ball = __ballot(lm == wm);
    int first = __ffsll(ball) - 1;
    if (lane == first){
      if      (w0 == wm) w0 = NEG;
      else if (w1 == wm) w1 = NEG;
      else if (w2 == wm) w2 = NEG;
      else               w3 = NEG;
    }
    thr = wm;
  }
  float s = 0.f;
  #pragma unroll
  for (int j = 0; j < 4; j++) s += (v[j] >= thr) ? v[j] : 0.f;
  #pragma unroll
  for (int off = 32; off; off >>= 1) s += __shfl_xor(s, off, 64);
  const float d = s * (1.0f / NB);   // matches ref: res / (sum/n)
  f32x4 o;
  #pragma unroll
  for (int j = 0; j < 4; j++) o[j] = (v[j] >= thr) ? v[j] / d : 0.f;
  p0[lane] = o;                      // final gates overwrite partial 0
}

// ---------------- K3: gated main GEMM, bf16 MFMA 16x16x32 -------------------
// block: 128 rows x 128 cols (one output block q). 4 waves, each 64x64.
// gate folded into A during LDS staging (native bf16 casts -> cvt_pk). BK=64.
__global__ __launch_bounds__(256) void main_gemm(
    const unsigned short* __restrict__ xb,
    const unsigned short* __restrict__ wt,
    const float* __restrict__ g,
    const float* __restrict__ bias,
    float* __restrict__ out)
{
  __shared__ unsigned short xa[128][72];   // [row][k] gated bf16, +8 pad
  __shared__ unsigned short wb[128][72];   // [n][k]   bf16 (W^T), +8 pad
  __shared__ float gl[128 * 17];           // gates [row][p], stride 17

  const int q    = blockIdx.x;             // output block col 0..15
  const int b0   = blockIdx.y * 128;       // batch row tile
  const int t    = threadIdx.x;
  const int lane = t & 63;
  const int wid  = t >> 6;
  const int wr   = (wid >> 1) * 64;
  const int wc   = (wid & 1) * 64;
  const int l15  = lane & 15;
  const int l4   = lane >> 4;

  for (int e = t; e < 128 * 16; e += 256){
    const int r = e >> 4, p = e & 15;
    gl[r * 17 + p] = g[(size_t)(b0 + r) * NB + p * 16 + q];
  }

  f32x4 acc[4][4];
  #pragma unroll
  for (int m = 0; m < 4; m++)
    #pragma unroll
    for (int n = 0; n < 4; n++) acc[m][n] = (f32x4)0.0f;

  const int row_s = t >> 1;
  const int half  = t & 1;

  for (int kp = 0; kp < 32; kp++){         // 32 K-slices of 64 (p = kp>>1)
    const int p = kp >> 1;
    __syncthreads();                        // protect LDS reuse (covers gl on kp=0)
    { // stage gated A: xb * gate -> bf16 (lshl + mul + cvt_pk)
      const float gate = gl[row_s * 17 + p];
      const unsigned short* src = &xb[(size_t)(b0 + row_s) * DIN + kp * 64 + half * 32];
      unsigned short* dst = &xa[row_s][half * 32];
      #pragma unroll
      for (int c = 0; c < 4; c++){
        u16x8 u = *(const u16x8*)(src + c * 8);
        u16x8 o;
        #pragma unroll
        for (int j = 0; j < 8; j++) o[j] = f2bf_c(bf2f(u[j]) * gate);
        *(u16x8*)(dst + c * 8) = o;
      }
    }
    { // stage B: W^T tile copy
      const unsigned short* src = &wt[(size_t)(q * 128 + row_s) * DIN + kp * 64 + half * 32];
      unsigned short* dst = &wb[row_s][half * 32];
      #pragma unroll
      for (int c = 0; c < 4; c++)
        *(u16x8*)(dst + c * 8) = *(const u16x8*)(src + c * 8);
    }
    __syncthreads();
    #pragma unroll
    for (int ksi = 0; ksi < 2; ksi++){
      const int kk = ksi * 32 + l4 * 8;
      bf16x8 a[4], b[4];
      #pragma unroll
      for (int m = 0; m < 4; m++)
        a[m] = *(const bf16x8*)&xa[wr + m * 16 + l15][kk];
      #pragma unroll
      for (int n = 0; n < 4; n++)
        b[n] = *(const bf16x8*)&wb[wc + n * 16 + l15][kk];
      #pragma unroll
      for (int m = 0; m < 4; m++)
        #pragma unroll
        for (int n = 0; n < 4; n++)
          acc[m][n] = __builtin_amdgcn_mfma_f32_16x16x32_bf16(a[m], b[n], acc[m][n], 0, 0, 0);
    }
  }

  #pragma unroll
  for (int n = 0; n < 4; n++){
    const int col = q * 128 + wc + n * 16 + l15;
    const float bv = bias[col];
    #pragma unroll
    for (int m = 0; m < 4; m++){
      #pragma unroll
      for (int r = 0; r < 4; r++){
        const int row = b0 + wr + m * 16 + l4 * 4 + r;   // C/D: row=(lane>>4)*4+reg
        out[(size_t)row * DOUT + col] = acc[m][n][r] + bv;
      }
    }
  }
}

// ---------------- launch -----------------------------------------------------
extern "C" void kernel_launch(void* const* d_in, const int* in_sizes, int n_in,
                              void* d_out, int out_size, void* d_ws, size_t ws_size,
                              hipStream_t stream)
{
  const float* x    = (const float*)d_in[0];
  const float* w    = (const float*)d_in[1];
  const float* bias = (const float*)d_in[2];
  const float* gw   = (const float*)d_in[3];
  const float* gb   = (const float*)d_in[4];
  float* out = (float*)d_out;

  // ws layout: [0,16MB) gate partials (partial 0 becomes final gates),
  //            [16MB,24MB) W^T bf16, [24MB,56MB) x bf16
  float*          part = (float*)d_ws;
  unsigned short* wtb  = (unsigned short*)((char*)d_ws + (size_t)16 * 1024 * 1024);
  unsigned short* xbb  = (unsigned short*)((char*)d_ws + (size_t)24 * 1024 * 1024);

  conv_wt  <<<dim3(DIN / 64, DOUT / 64), 256, 0, stream>>>(w, wtb);
  gate_gemm<<<dim3(BATCH / 32, 2), 256, 0, stream>>>(x, gw, part, xbb);
  topk     <<<BATCH / 4, 256, 0, stream>>>(part, gb);
  main_gemm<<<dim3(16, BATCH / 128), 256, 0, stream>>>(xbb, wtb, part, bias, out);
}

// Round 5
// 305.499 us; speedup vs baseline: 1.1159x; 1.1159x over previous
//
#include <hip/hip_runtime.h>
#include <hip/hip_bf16.h>
#include <stdint.h>

#define BATCH  8192
#define DIN    2048
#define DOUT   2048
#define NB     256
#define KSEL   26      // ceil(0.1*256)
#define GDELTA 1e-4f   // top-k boundary refine threshold (~36 sigma of MFMA-vs-exact error)

typedef __attribute__((ext_vector_type(2))) float f32x2;
typedef __attribute__((ext_vector_type(4))) float f32x4;
typedef __attribute__((ext_vector_type(16))) float f32x16;
typedef __attribute__((ext_vector_type(8))) __bf16 bf16x8;
typedef __attribute__((ext_vector_type(8))) unsigned short u16x8;
typedef __attribute__((ext_vector_type(4))) unsigned short u16x4;

__device__ __forceinline__ float bf2f(unsigned short u){
  union { unsigned int i; float f; } v; v.i = ((unsigned int)u) << 16; return v.f;
}
__device__ __forceinline__ unsigned short f2bf(float f){
  union { float f; unsigned int i; } v; v.f = f;
  unsigned int x = v.i;
  return (unsigned short)((x + 0x7FFFu + ((x >> 16) & 1u)) >> 16);  // RNE
}
// native cast path — compiler emits v_cvt_pk_bf16_f32 for pairs (RNE)
__device__ __forceinline__ unsigned short f2bf_c(float f){
  __bf16 b = (__bf16)f;
  union { __bf16 b; unsigned short u; } v; v.b = b; return v.u;
}

// ---------------- K0b: W -> W^T bf16 (wt[n][k] = W[k][n]) ----------------
__global__ __launch_bounds__(256) void conv_wt(const float* __restrict__ w, unsigned short* __restrict__ wt)
{
  __shared__ float tl[64][65];
  const int k0 = blockIdx.x * 64;
  const int n0 = blockIdx.y * 64;
  const int c  = threadIdx.x & 63;
  const int r4 = threadIdx.x >> 6;
  #pragma unroll
  for (int i = 0; i < 16; i++){
    const int r = r4 * 16 + i;
    tl[r][c] = w[(size_t)(k0 + r) * DOUT + n0 + c];
  }
  __syncthreads();
  #pragma unroll
  for (int i = 0; i < 16; i++){
    const int n = r4 * 16 + i;
    wt[(size_t)(n0 + n) * DIN + k0 + c] = f2bf(tl[c][n]);
  }
}

// ---------------- K0c: gw -> transposed hi/lo bf16 split --------------------
// ghiT[n][k] = bf16(gw[k][n]); gloT[n][k] = bf16(gw[k][n] - ghiT) (exact resid)
__global__ __launch_bounds__(256) void conv_gwt(const float* __restrict__ gw,
    unsigned short* __restrict__ ghiT, unsigned short* __restrict__ gloT)
{
  __shared__ float tl[64][65];
  const int k0 = blockIdx.x * 64;
  const int n0 = blockIdx.y * 64;
  const int c  = threadIdx.x & 63;
  const int r4 = threadIdx.x >> 6;
  #pragma unroll
  for (int i = 0; i < 16; i++){
    const int r = r4 * 16 + i;
    tl[r][c] = gw[(size_t)(k0 + r) * NB + n0 + c];
  }
  __syncthreads();
  #pragma unroll
  for (int i = 0; i < 16; i++){
    const int n = r4 * 16 + i;
    const float v = tl[c][n];
    const unsigned short h = f2bf_c(v);
    ghiT[(size_t)(n0 + n) * DIN + k0 + c] = h;
    gloT[(size_t)(n0 + n) * DIN + k0 + c] = f2bf_c(v - bf2f(h));
  }
}

// ---------------- K1: gate GEMM via bf16 MFMA (3-term hi/lo split) ----------
// out = x_hi@g_hi + x_hi@g_lo + x_lo@g_hi  (error vs exact f32 ~3e-6; boundary
// rows are exactly recomputed by refine()). Block: 32 rows x 256 cols, full
// K=2048, BK=32, double-buffered LDS. 4 waves; wave tile 32x64 (n=2 frags of
// 32x32x16). A-staging converts x f32 -> hi/lo bf16 on the fly and emits
// xb = x_hi (bf16 x for main_gemm). grid = 256 (1 block/CU).
__global__ __launch_bounds__(256) void gate_mfma(
    const float* __restrict__ x,
    const unsigned short* __restrict__ ghiT,
    const unsigned short* __restrict__ gloT,
    float* __restrict__ part,
    unsigned short* __restrict__ xb)
{
  __shared__ unsigned short Ah[2][32][40], Al[2][32][40];   // stride 80B: minimal-conflict b128
  __shared__ unsigned short Bh[2][256][40], Bl[2][256][40];

  const int b0   = blockIdx.x * 32;
  const int t    = threadIdx.x;
  const int lane = t & 63;
  const int wv   = t >> 6;            // wave: cols wv*64 .. +63
  const int l31  = lane & 31;
  const int lk   = (lane >> 5) * 8;   // k sub-offset within 16-k chunk

  // staging maps
  const int sr = t >> 3;              // A row 0..31
  const int sk = (t & 7) * 4;         // A k offset (f32x4)
  const int bc = t >> 2;              // B col base 0..63 (x4 groups of 64)
  const int bk = (t & 3) * 8;         // B k chunk (u16x8)

  f32x16 acc[2];
  acc[0] = (f32x16)0.f; acc[1] = (f32x16)0.f;

  auto STAGE = [&](int bb, int k0){
    // A: x f32 -> hi/lo bf16, emit xb = x_hi
    f32x4 a = *(const f32x4*)&x[(size_t)(b0 + sr) * DIN + k0 + sk];
    u16x4 hi4, lo4;
    #pragma unroll
    for (int j = 0; j < 4; j++){
      const unsigned short h = f2bf_c(a[j]);
      hi4[j] = h;
      lo4[j] = f2bf_c(a[j] - bf2f(h));
    }
    *(u16x4*)&Ah[bb][sr][sk] = hi4;
    *(u16x4*)&Al[bb][sr][sk] = lo4;
    *(u16x4*)&xb[(size_t)(b0 + sr) * DIN + k0 + sk] = hi4;
    // B: g^T hi/lo tiles (L2-resident, 64B-coalesced per 4 lanes)
    #pragma unroll
    for (int p = 0; p < 4; p++){
      const int col = bc + p * 64;
      u16x8 vh = *(const u16x8*)&ghiT[(size_t)col * DIN + k0 + bk];
      *(u16x8*)&Bh[bb][col][bk] = vh;
      u16x8 vl = *(const u16x8*)&gloT[(size_t)col * DIN + k0 + bk];
      *(u16x8*)&Bl[bb][col][bk] = vl;
    }
  };

  STAGE(0, 0);
  __syncthreads();
  int cur = 0;
  for (int ks = 0; ks < 64; ks++){
    if (ks < 63) STAGE(cur ^ 1, (ks + 1) * 32);   // prefetch next tile
    bf16x8 ah[2], al[2], bh[2][2], bl[2][2];
    #pragma unroll
    for (int kh = 0; kh < 2; kh++){
      const int ko = kh * 16 + lk;
      ah[kh] = *(const bf16x8*)&Ah[cur][l31][ko];
      al[kh] = *(const bf16x8*)&Al[cur][l31][ko];
      #pragma unroll
      for (int n = 0; n < 2; n++){
        bh[n][kh] = *(const bf16x8*)&Bh[cur][wv * 64 + n * 32 + l31][ko];
        bl[n][kh] = *(const bf16x8*)&Bl[cur][wv * 64 + n * 32 + l31][ko];
      }
    }
    #pragma unroll
    for (int n = 0; n < 2; n++)
      #pragma unroll
      for (int kh = 0; kh < 2; kh++){
        acc[n] = __builtin_amdgcn_mfma_f32_32x32x16_bf16(ah[kh], bh[n][kh], acc[n], 0, 0, 0);
        acc[n] = __builtin_amdgcn_mfma_f32_32x32x16_bf16(ah[kh], bl[n][kh], acc[n], 0, 0, 0);
        acc[n] = __builtin_amdgcn_mfma_f32_32x32x16_bf16(al[kh], bh[n][kh], acc[n], 0, 0, 0);
      }
    __syncthreads();
    cur ^= 1;
  }

  // C/D 32x32: col = lane&31, row = (reg&3) + 8*(reg>>2) + 4*(lane>>5)
  #pragma unroll
  for (int n = 0; n < 2; n++){
    const int col = wv * 64 + n * 32 + l31;
    #pragma unroll
    for (int r = 0; r < 16; r++){
      const int row = (r & 3) + 8 * (r >> 2) + 4 * (lane >> 5);
      part[(size_t)(b0 + row) * NB + col] = acc[n][r];
    }
  }
}

// ---------------- K2: top-26 threshold + renorm + boundary flag -------------
// 27 max-extractions: thr = 26th, nxt = 27th; flag row if gap < GDELTA.
__global__ __launch_bounds__(256) void topk(float* __restrict__ part,
    const float* __restrict__ gb, int* __restrict__ flags)
{
  const int lane = threadIdx.x & 63;
  const int row  = blockIdx.x * 4 + (threadIdx.x >> 6);
  f32x4* p0 = (f32x4*)&part[(size_t)row * NB];
  const f32x4* gbv = (const f32x4*)gb;
  f32x4 v = p0[lane] + gbv[lane];

  const float NEG = -3.402823466e38f;
  float w0 = v[0], w1 = v[1], w2 = v[2], w3 = v[3];
  float thr = 0.f, nxt = 0.f;
  for (int it = 0; it < KSEL + 1; it++){
    float lm = fmaxf(fmaxf(w0, w1), fmaxf(w2, w3));
    float wm = lm;
    #pragma unroll
    for (int off = 32; off; off >>= 1) wm = fmaxf(wm, __shfl_xor(wm, off, 64));
    unsigned long long ball = __ballot(lm == wm);
    int first = __ffsll(ball) - 1;
    if (lane == first){
      if      (w0 == wm) w0 = NEG;
      else if (w1 == wm) w1 = NEG;
      else if (w2 == wm) w2 = NEG;
      else               w3 = NEG;
    }
    if (it < KSEL) thr = wm; else nxt = wm;
  }
  if (lane == 0) flags[row] = (thr - nxt < GDELTA) ? 1 : 0;

  float s = 0.f;
  #pragma unroll
  for (int j = 0; j < 4; j++) s += (v[j] >= thr) ? v[j] : 0.f;
  #pragma unroll
  for (int off = 32; off; off >>= 1) s += __shfl_xor(s, off, 64);
  const float d = s * (1.0f / NB);
  f32x4 o;
  #pragma unroll
  for (int j = 0; j < 4; j++) o[j] = (v[j] >= thr) ? v[j] / d : 0.f;
  p0[lane] = o;
}

// ---------------- K2b: exact recompute of boundary-ambiguous rows -----------
// Reproduces the R1-R4 bit-exact chain: sequential fmaf k=0..1023 per split,
// v = (p0 + p1) + gb, then the same 26-extraction top-k + renorm.
__global__ __launch_bounds__(256) void refine(
    const float* __restrict__ x, const float* __restrict__ gw,
    const float* __restrict__ gb, const int* __restrict__ flags,
    float* __restrict__ part)
{
  const int lane = threadIdx.x & 63;
  const int row  = blockIdx.x * 4 + (threadIdx.x >> 6);
  if (!flags[row]) return;

  f32x4 acc0 = (f32x4)0.f, acc1 = (f32x4)0.f;
  const float* xp = &x[(size_t)row * DIN];
  #pragma unroll 8
  for (int k = 0; k < 1024; k++){
    const float xv = xp[k];
    const f32x4 wv = *(const f32x4*)&gw[(size_t)k * NB + lane * 4];
    #pragma unroll
    for (int j = 0; j < 4; j++) acc0[j] = fmaf(xv, wv[j], acc0[j]);
  }
  #pragma unroll 8
  for (int k = 1024; k < 2048; k++){
    const float xv = xp[k];
    const f32x4 wv = *(const f32x4*)&gw[(size_t)k * NB + lane * 4];
    #pragma unroll
    for (int j = 0; j < 4; j++) acc1[j] = fmaf(xv, wv[j], acc1[j]);
  }
  const f32x4 gbv = *(const f32x4*)&gb[lane * 4];
  f32x4 v;
  #pragma unroll
  for (int j = 0; j < 4; j++) v[j] = acc0[j] + acc1[j] + gbv[j];

  const float NEG = -3.402823466e38f;
  float w0 = v[0], w1 = v[1], w2 = v[2], w3 = v[3];
  float thr = 0.f;
  for (int it = 0; it < KSEL; it++){
    float lm = fmaxf(fmaxf(w0, w1), fmaxf(w2, w3));
    float wm = lm;
    #pragma unroll
    for (int off = 32; off; off >>= 1) wm = fmaxf(wm, __shfl_xor(wm, off, 64));
    unsigned long long ball = __ballot(lm == wm);
    int first = __ffsll(ball) - 1;
    if (lane == first){
      if      (w0 == wm) w0 = NEG;
      else if (w1 == wm) w1 = NEG;
      else if (w2 == wm) w2 = NEG;
      else               w3 = NEG;
    }
    thr = wm;
  }
  float s = 0.f;
  #pragma unroll
  for (int j = 0; j < 4; j++) s += (v[j] >= thr) ? v[j] : 0.f;
  #pragma unroll
  for (int off = 32; off; off >>= 1) s += __shfl_xor(s, off, 64);
  const float d = s * (1.0f / NB);
  f32x4 o;
  #pragma unroll
  for (int j = 0; j < 4; j++) o[j] = (v[j] >= thr) ? v[j] / d : 0.f;
  *(f32x4*)&part[(size_t)row * NB + lane * 4] = o;
}

// ---------------- K3: gated main GEMM, bf16 MFMA 16x16x32 -------------------
// block: 128 rows x 128 cols (one output block q). 4 waves, each 64x64.
// gate folded into A during LDS staging (native bf16 casts -> cvt_pk). BK=64.
__global__ __launch_bounds__(256) void main_gemm(
    const unsigned short* __restrict__ xb,
    const unsigned short* __restrict__ wt,
    const float* __restrict__ g,
    const float* __restrict__ bias,
    float* __restrict__ out)
{
  __shared__ unsigned short xa[128][72];   // [row][k] gated bf16, +8 pad
  __shared__ unsigned short wb[128][72];   // [n][k]   bf16 (W^T), +8 pad
  __shared__ float gl[128 * 17];           // gates [row][p], stride 17

  const int q    = blockIdx.x;             // output block col 0..15
  const int b0   = blockIdx.y * 128;       // batch row tile
  const int t    = threadIdx.x;
  const int lane = t & 63;
  const int wid  = t >> 6;
  const int wr   = (wid >> 1) * 64;
  const int wc   = (wid & 1) * 64;
  const int l15  = lane & 15;
  const int l4   = lane >> 4;

  for (int e = t; e < 128 * 16; e += 256){
    const int r = e >> 4, p = e & 15;
    gl[r * 17 + p] = g[(size_t)(b0 + r) * NB + p * 16 + q];
  }

  f32x4 acc[4][4];
  #pragma unroll
  for (int m = 0; m < 4; m++)
    #pragma unroll
    for (int n = 0; n < 4; n++) acc[m][n] = (f32x4)0.0f;

  const int row_s = t >> 1;
  const int half  = t & 1;

  for (int kp = 0; kp < 32; kp++){         // 32 K-slices of 64 (p = kp>>1)
    const int p = kp >> 1;
    __syncthreads();                        // protect LDS reuse (covers gl on kp=0)
    { // stage gated A: xb * gate -> bf16 (lshl + mul + cvt_pk)
      const float gate = gl[row_s * 17 + p];
      const unsigned short* src = &xb[(size_t)(b0 + row_s) * DIN + kp * 64 + half * 32];
      unsigned short* dst = &xa[row_s][half * 32];
      #pragma unroll
      for (int c = 0; c < 4; c++){
        u16x8 u = *(const u16x8*)(src + c * 8);
        u16x8 o;
        #pragma unroll
        for (int j = 0; j < 8; j++) o[j] = f2bf_c(bf2f(u[j]) * gate);
        *(u16x8*)(dst + c * 8) = o;
      }
    }
    { // stage B: W^T tile copy
      const unsigned short* src = &wt[(size_t)(q * 128 + row_s) * DIN + kp * 64 + half * 32];
      unsigned short* dst = &wb[row_s][half * 32];
      #pragma unroll
      for (int c = 0; c < 4; c++)
        *(u16x8*)(dst + c * 8) = *(const u16x8*)(src + c * 8);
    }
    __syncthreads();
    #pragma unroll
    for (int ksi = 0; ksi < 2; ksi++){
      const int kk = ksi * 32 + l4 * 8;
      bf16x8 a[4], b[4];
      #pragma unroll
      for (int m = 0; m < 4; m++)
        a[m] = *(const bf16x8*)&xa[wr + m * 16 + l15][kk];
      #pragma unroll
      for (int n = 0; n < 4; n++)
        b[n] = *(const bf16x8*)&wb[wc + n * 16 + l15][kk];
      #pragma unroll
      for (int m = 0; m < 4; m++)
        #pragma unroll
        for (int n = 0; n < 4; n++)
          acc[m][n] = __builtin_amdgcn_mfma_f32_16x16x32_bf16(a[m], b[n], acc[m][n], 0, 0, 0);
    }
  }

  #pragma unroll
  for (int n = 0; n < 4; n++){
    const int col = q * 128 + wc + n * 16 + l15;
    const float bv = bias[col];
    #pragma unroll
    for (int m = 0; m < 4; m++){
      #pragma unroll
      for (int r = 0; r < 4; r++){
        const int row = b0 + wr + m * 16 + l4 * 4 + r;   // C/D: row=(lane>>4)*4+reg
        out[(size_t)row * DOUT + col] = acc[m][n][r] + bv;
      }
    }
  }
}

// ---------------- launch -----------------------------------------------------
extern "C" void kernel_launch(void* const* d_in, const int* in_sizes, int n_in,
                              void* d_out, int out_size, void* d_ws, size_t ws_size,
                              hipStream_t stream)
{
  const float* x    = (const float*)d_in[0];
  const float* w    = (const float*)d_in[1];
  const float* bias = (const float*)d_in[2];
  const float* gw   = (const float*)d_in[3];
  const float* gb   = (const float*)d_in[4];
  float* out = (float*)d_out;

  // ws layout: [0,8M) part/gates, [8M,16M) W^T bf16, [16M,48M) x_hi bf16 (=xb),
  //            [48M,49M) g_hi^T bf16, [49M,50M) g_lo^T bf16, [50M,..) flags
  char* wsb = (char*)d_ws;
  float*          part = (float*)wsb;
  unsigned short* wtb  = (unsigned short*)(wsb + (size_t)8  * 1024 * 1024);
  unsigned short* xbb  = (unsigned short*)(wsb + (size_t)16 * 1024 * 1024);
  unsigned short* ghiT = (unsigned short*)(wsb + (size_t)48 * 1024 * 1024);
  unsigned short* gloT = (unsigned short*)(wsb + (size_t)49 * 1024 * 1024);
  int*            flg  = (int*)           (wsb + (size_t)50 * 1024 * 1024);

  conv_wt  <<<dim3(DIN / 64, DOUT / 64), 256, 0, stream>>>(w, wtb);
  conv_gwt <<<dim3(DIN / 64, NB / 64),   256, 0, stream>>>(gw, ghiT, gloT);
  gate_mfma<<<BATCH / 32, 256, 0, stream>>>(x, ghiT, gloT, part, xbb);
  topk     <<<BATCH / 4, 256, 0, stream>>>(part, gb, flg);
  refine   <<<BATCH / 4, 256, 0, stream>>>(x, gw, gb, flg, part);
  main_gemm<<<dim3(16, BATCH / 128), 256, 0, stream>>>(xbb, wtb, part, bias, out);
}